// Round 13
// baseline (164.750 us; speedup 1.0000x reference)
//
#include <hip/hip_runtime.h>
#include <hip/hip_bf16.h>

#define NN 16384          // sequence length
#define NC 16             // layer channels
#define NPOSTOT 131072    // 8 * 16384
#define NLAY 29           // gated layers
#define LSTR 24           // LDS row stride in shorts (48 B, 16B-aligned rows)

typedef float4 f4;
typedef short bf16x8 __attribute__((ext_vector_type(8)));
typedef float f32x4 __attribute__((ext_vector_type(4)));
typedef float f32x16 __attribute__((ext_vector_type(16)));

// prepack element offsets (in shorts)
#define OFF_C  0                        // conv A-frags: [29][2 taps][512]
#define OFF_R  (NLAY * 1024)            // 29696: 1x1 A-frags: [29][512]
#define OFF_WA (OFF_R + NLAY * 512)     // 44544: head Wa frags
#define OFF_WO (OFF_WA + 2048)          // 46592: head Wo frags
#define PK_TOT (OFF_WO + 16384)         // 62976 shorts

// stream-slot -> actual channel permutation (involution; swaps ch 4-7 <-> 8-11)
__host__ __device__ constexpr int PERM(int s) {
    return (s & 3) | ((s & 4) << 1) | ((s & 8) >> 1);
}

static __device__ __forceinline__ short to_bf16(float f) {
    __hip_bfloat16 h = __float2bfloat16(f);   // RNE
    short s;
    __builtin_memcpy(&s, &h, 2);
    return s;
}
static __device__ __forceinline__ float from_bf16(short s) {
    unsigned int u = ((unsigned int)(unsigned short)s) << 16;
    float f;
    __builtin_memcpy(&f, &u, 4);
    return f;
}

// ---------------- weight prepack into MFMA A-fragments (bf16) -----------------
// 32x32x16 conv: A rows 0-15 = Wf out-ch, 16-31 = Wg out-ch; lane l holds
// row l&31, k-slot (hi=l>>5, j) -> actual input ch PERM(hi*8+j).
// 32x32x16 1x1:  A rows 0-15 = Wr out-ch (row m = actual out m), 16-31 zero;
// k-slot (hi,j) -> z stream-slot hi*8+j -> actual ch PERM(hi*8+j).
// head Wa (16x16x32): k-slot (h,j) -> actual ch PERM(h*8+j) for k<16.
// head Wo: unchanged.
__global__ __launch_bounds__(256) void prepack_k(
    const float* __restrict__ Wf, const float* __restrict__ Wg,
    const float* __restrict__ Wr, const float* __restrict__ Wa,
    const float* __restrict__ Wo, short* __restrict__ pk)
{
    const int i = blockIdx.x * 256 + threadIdx.x;
    if (i >= PK_TOT) return;
    float val;
    if (i < OFF_R) {                                // conv A-frags
        const int j = i >> 10, r = i & 1023, tp = r >> 9, rr = r & 511;
        const int l = rr >> 3, j8 = rr & 7;
        const int row = l & 31, hi = l >> 5;
        const int c = PERM(hi * 8 + j8);
        val = (row < 16) ? Wf[((j * 16 + row) * 16 + c) * 2 + tp]
                         : Wg[((j * 16 + (row - 16)) * 16 + c) * 2 + tp];
    } else if (i < OFF_WA) {                        // 1x1 A-frags
        const int i2 = i - OFF_R;
        const int j = i2 >> 9, rr = i2 & 511, l = rr >> 3, j8 = rr & 7;
        const int row = l & 31, hi = l >> 5;
        val = (row < 16) ? Wr[j * 256 + row * 16 + PERM(hi * 8 + j8)] : 0.0f;
    } else if (i < OFF_WO) {                        // Wa frags (4 m-tiles)
        const int i2 = i - OFF_WA;
        const int mt = i2 >> 9, rr = i2 & 511, l = rr >> 3, j8 = rr & 7;
        const int og = mt * 16 + (l & 15), h = l >> 4;
        const int k = h * 8 + j8;
        val = (k < 16) ? Wa[og * 16 + PERM(k)] : 0.0f;
    } else {                                        // Wo frags (16 q-tiles x 2)
        const int i2 = i - OFF_WO;
        const int qt = i2 >> 10, hf = (i2 >> 9) & 1, rr = i2 & 511;
        const int l = rr >> 3, j8 = rr & 7;
        const int q = qt * 16 + (l & 15), h = l >> 4;
        const int kg = hf * 32 + (j8 >> 2) * 16 + h * 4 + (j8 & 3);
        val = Wo[q * 64 + kg];
    }
    pk[i] = to_bf16(val);
}

// ---------------- 32x32 gated layer core --------------------------------------
// One wave computes f,g,z,out for a 32-position tile. acc reg r (r<8) = f at
// lane's stream slot s0+r; reg r+8 = g at same slot. 1x1 D reg r = out at
// slot s0+r. res/cur are the lane's 8 stream-slot values.
static __device__ __forceinline__ void layer32(
    bf16x8 b0v, bf16x8 b1v, const short* __restrict__ pk, int j,
    const float* __restrict__ bfA, const float* __restrict__ bgA,
    const float* __restrict__ brA, int lane, int hi4,
    float* res, bf16x8& cur)
{
    const bf16x8 a0 = *(const bf16x8*)(pk + OFF_C + j * 1024 + lane * 8);
    const bf16x8 a1 = *(const bf16x8*)(pk + OFF_C + j * 1024 + 512 + lane * 8);
    const bf16x8 ar = *(const bf16x8*)(pk + OFF_R + j * 512 + lane * 8);
    const f4 bf0 = *(const f4*)(bfA + j * 16 + hi4);
    const f4 bf1 = *(const f4*)(bfA + j * 16 + 8 + hi4);
    const f4 bg0 = *(const f4*)(bgA + j * 16 + hi4);
    const f4 bg1 = *(const f4*)(bgA + j * 16 + 8 + hi4);

    f32x16 acc = {bf0.x, bf0.y, bf0.z, bf0.w, bf1.x, bf1.y, bf1.z, bf1.w,
                  bg0.x, bg0.y, bg0.z, bg0.w, bg1.x, bg1.y, bg1.z, bg1.w};
    acc = __builtin_amdgcn_mfma_f32_32x32x16_bf16(a0, b0v, acc, 0, 0, 0);
    acc = __builtin_amdgcn_mfma_f32_32x32x16_bf16(a1, b1v, acc, 0, 0, 0);

    bf16x8 bz;
#pragma unroll
    for (int r = 0; r < 8; ++r) {
        // z = tanh(f)*sigmoid(g) = (e^{2f}-1) / ((e^{2f}+1)(1+e^{-g}))
        const float ef = __expf(2.0f * fminf(acc[r], 43.0f));
        const float eg = __expf(-acc[r + 8]);
        const float den = fmaf(ef, eg, ef) + (eg + 1.0f);
        bz[r] = to_bf16((ef - 1.0f) * __builtin_amdgcn_rcpf(den));
    }

    const f4 br0 = *(const f4*)(brA + j * 16 + hi4);
    const f4 br1 = *(const f4*)(brA + j * 16 + 8 + hi4);
    f32x16 cr = {br0.x, br0.y, br0.z, br0.w, br1.x, br1.y, br1.z, br1.w,
                 0.0f, 0.0f, 0.0f, 0.0f, 0.0f, 0.0f, 0.0f, 0.0f};
    const f32x16 o = __builtin_amdgcn_mfma_f32_32x32x16_bf16(ar, bz, cr, 0, 0, 0);

#pragma unroll
    for (int r = 0; r < 8; ++r) res[r] += o[r];
#pragma unroll
    for (int r = 0; r < 8; ++r) cur[r] = to_bf16(res[r]);
}

// ---------------- fused multi-layer segment kernel ----------------------------
// blockDim = Wp threads = Wp/64 waves, each wave owns 2 32-pos tiles (rows
// wv*32.. and +W*32..). Residual fp32 + its bf16 image (cur) in registers;
// tap1 of every conv is cur (no LDS read); tap0 read from LDS/global.
struct SegCfg { int d[8]; int nl; int jbase; int H; int l0; int tout; };

constexpr SegCfg CFGS[12] = {
    {{2, 4, 8, 16, 32, 64, 0, 0},  6, 0,  128, 1, 128},  // K1: L0 + j0..j5
    {{128, 0, 0, 0, 0, 0, 0, 0},   1, 6,  0,   0, 256},  // K2
    {{256, 0, 0, 0, 0, 0, 0, 0},   1, 7,  0,   0, 256},  // K3
    {{512, 1, 2, 4, 8, 16, 32, 0}, 7, 8,  64,  0, 128},  // K4
    {{64, 0, 0, 0, 0, 0, 0, 0},    1, 15, 0,   0, 256},  // K5
    {{128, 0, 0, 0, 0, 0, 0, 0},   1, 16, 0,   0, 256},  // K6
    {{256, 0, 0, 0, 0, 0, 0, 0},   1, 17, 0,   0, 256},  // K7
    {{512, 1, 2, 4, 8, 16, 32, 0}, 7, 18, 64,  0, 128},  // K8
    {{64, 0, 0, 0, 0, 0, 0, 0},    1, 25, 0,   0, 256},  // K9
    {{128, 0, 0, 0, 0, 0, 0, 0},   1, 26, 0,   0, 256},  // K10
    {{256, 0, 0, 0, 0, 0, 0, 0},   1, 27, 0,   0, 256},  // K11
    {{512, 0, 0, 0, 0, 0, 0, 0},   1, 28, 0,   0, 256},  // K12
};

template<int KI>
__global__ __launch_bounds__(CFGS[KI].tout + CFGS[KI].H)
void fused_t(const short* __restrict__ src, const float* __restrict__ x,
             const float* __restrict__ W0, const float* __restrict__ b0,
             short* __restrict__ dst, const short* __restrict__ pk,
             const float* __restrict__ bfA, const float* __restrict__ bgA,
             const float* __restrict__ brA)
{
    constexpr SegCfg cfg = CFGS[KI];
    constexpr int H = cfg.H;
    constexpr int TOUT = cfg.tout;
    constexpr int Wp = TOUT + H;
    constexpr int W = Wp / 64;             // waves per block
    constexpr bool MULTI = (cfg.nl > 1);
    constexpr int LDSSZ = MULTI ? 2 * Wp * LSTR : 8;
    __shared__ short lds[LDSSZ];
    short* ldsA = lds;
    short* ldsB = lds + (MULTI ? Wp * LSTR : 0);

    const int t = threadIdx.x, lane = t & 63, wv = t >> 6;
    const int hi = lane >> 5, hi4 = hi * 4, s0 = hi * 8;
    const int p31 = lane & 31;
    const int pbase = blockIdx.x * TOUT;
    const int bb = pbase >> 14, n0 = pbase & (NN - 1);
    const float* xrow = x + (size_t)bb * NN;
    const short* srow = src + (size_t)bb * NN * NC;

    const int l0r = wv * 32 + p31;         // tile-0 LDS row
    const int l1r = l0r + W * 32;          // tile-1 LDS row
    const int nA = n0 - H + l0r;
    const int nB = n0 - H + l1r;

    float res0[8], res1[8];
    bf16x8 cur0, cur1;

    // ---- phase 0: first layer of the group, inputs from GLOBAL / L0 ----
    {
        constexpr int d = cfg.d[0];
        constexpr int j = cfg.jbase;
        auto tile0 = [&](int l, int n, float* res, bf16x8& cur) {
            const int ns = n - d;
            bf16x8 b0v = {0, 0, 0, 0, 0, 0, 0, 0};
            bf16x8 b1v = {0, 0, 0, 0, 0, 0, 0, 0};
            if (cfg.l0) {
                if (ns >= 0) {     // layer-0 output at tap position
                    const float xs = xrow[ns] * (1.0f / 32768.0f);
                    const float xm = (ns >= 1) ? xrow[ns - 1] * (1.0f / 32768.0f) : 0.0f;
#pragma unroll
                    for (int q = 0; q < 8; ++q) {
                        const int c = PERM(s0 + q);
                        b0v[q] = to_bf16(xs + fmaf(W0[c * 2], xm,
                                          fmaf(W0[c * 2 + 1], xs, b0[c])));
                    }
                }
                if (n >= 0) {      // layer-0 output at own position (fp32 kept)
                    const float xs = xrow[n] * (1.0f / 32768.0f);
                    const float xm = (n >= 1) ? xrow[n - 1] * (1.0f / 32768.0f) : 0.0f;
#pragma unroll
                    for (int q = 0; q < 8; ++q) {
                        const int c = PERM(s0 + q);
                        res[q] = xs + fmaf(W0[c * 2], xm,
                                  fmaf(W0[c * 2 + 1], xs, b0[c]));
                        b1v[q] = to_bf16(res[q]);
                    }
                } else {
#pragma unroll
                    for (int q = 0; q < 8; ++q) res[q] = 0.0f;
                }
            } else {
                if (ns >= 0) b0v = *(const bf16x8*)(srow + (size_t)ns * NC + s0);
                if (n >= 0)  b1v = *(const bf16x8*)(srow + (size_t)n * NC + s0);
#pragma unroll
                for (int q = 0; q < 8; ++q) res[q] = from_bf16(b1v[q]);
            }
            layer32(b0v, b1v, pk, j, bfA, bgA, brA, lane, hi4, res, cur);
            if (MULTI) *(bf16x8*)(ldsA + l * LSTR + s0) = cur;
        };
        tile0(l0r, nA, res0, cur0);
        tile0(l1r, nB, res1, cur1);
    }
    if (MULTI) __syncthreads();

    // ---- layers 1..nl-1: tap0 from LDS, tap1/residual from registers ----
    int curb = 0;
#pragma unroll
    for (int s = 1; s < cfg.nl; ++s) {
        const int d = cfg.d[s];
        const int j = cfg.jbase + s;
        const short* rb = curb ? ldsB : ldsA;
        short* wb = curb ? ldsA : ldsB;
        const bool wr = (s + 1 < cfg.nl);   // last layer: LDS write is dead

        auto tileL = [&](int l, int n, float* res, bf16x8& cur) {
            const int nt = n - d;
            int lt = l - d;
            if (lt < 0) lt = 0;             // garbage-region clamp (never read clean)
            bf16x8 b0v = {0, 0, 0, 0, 0, 0, 0, 0};
            if (nt >= 0) b0v = *(const bf16x8*)(rb + lt * LSTR + s0);
            layer32(b0v, cur, pk, j, bfA, bgA, brA, lane, hi4, res, cur);
            if (wr) *(bf16x8*)(wb + l * LSTR + s0) = cur;
        };
        tileL(l0r, nA, res0, cur0);
        tileL(l1r, nB, res1, cur1);
        if (wr) __syncthreads();
        curb ^= 1;
    }

    // ---- writeback of owned positions (H % 32 == 0 -> wave-uniform guard) ----
    if (l0r >= H)
        *(bf16x8*)(dst + ((size_t)bb * NN + nA) * NC + s0) = cur0;
    if (l1r >= H)
        *(bf16x8*)(dst + ((size_t)bb * NN + nB) * NC + s0) = cur1;
}

// ---------------- head: Wo frags in LDS; 512 threads, no spills ---------------
// fin stream is channel-permuted; Wa prepack folds the permutation.
__global__ __launch_bounds__(512, 2) void headm_k(
    const short* __restrict__ fin, const float* __restrict__ x,
    const int* __restrict__ lengths,
    const short* __restrict__ pka, const float* __restrict__ ba,
    const short* __restrict__ pko, const float* __restrict__ bo,
    float* __restrict__ out)
{
    __shared__ short ldsW[16384];            // all Wo fragments, 32 KB

    const int t = threadIdx.x;
    const int lane = t & 63;
    const int wv = t >> 6;
    const int i16 = lane & 15;
    const int h = lane >> 4;
    const int pos = blockIdx.x * 128 + wv * 16 + i16;
    const int b = pos >> 14;
    const int n = pos & (NN - 1);

    // cooperative stage of Wo frags: 512 threads x 4 x 16B coalesced
#pragma unroll
    for (int i = 0; i < 4; ++i)
        ((f4*)ldsW)[t + i * 512] = ((const f4*)pko)[t + i * 512];

    // B fragment for Wa: sk = relu(fin - xs), stream slots k=h*8+j (h<2)
    bf16x8 bs;
    if (h < 2) {
        const float xs = x[pos] * (1.0f / 32768.0f);
        const bf16x8 v = *(const bf16x8*)(fin + (size_t)pos * NC + h * 8);
#pragma unroll
        for (int j = 0; j < 8; ++j)
            bs[j] = to_bf16(fmaxf(from_bf16(v[j]) - xs, 0.0f));
    } else {
#pragma unroll
        for (int j = 0; j < 8; ++j) bs[j] = 0;
    }

    // Wa GEMM: ra = relu(...), 16 values/lane, lane-local for Wo B-frags
    float ra[16];
#pragma unroll
    for (int mt = 0; mt < 4; ++mt) {
        const bf16x8 aa = *(const bf16x8*)(pka + (mt * 64 + lane) * 8);
        const f4 bav = *(const f4*)(ba + mt * 16 + h * 4);
        f32x4 c = {bav.x, bav.y, bav.z, bav.w};
        c = __builtin_amdgcn_mfma_f32_16x16x32_bf16(aa, bs, c, 0, 0, 0);
#pragma unroll
        for (int r = 0; r < 4; ++r) ra[mt * 4 + r] = fmaxf(c[r], 0.0f);
    }
    bf16x8 blo, bhi;
#pragma unroll
    for (int j = 0; j < 8; ++j) { blo[j] = to_bf16(ra[j]); bhi[j] = to_bf16(ra[8 + j]); }

    __syncthreads();   // Wo frags staged

    // Wo GEMM: 16 q-tiles x (2 MFMA, K=64); A-frags from LDS; logits in VGPRs
    float lg[64];
#pragma unroll
    for (int qt = 0; qt < 16; ++qt) {
        const bf16x8 a0 = *(const bf16x8*)(ldsW + ((qt * 2 + 0) * 64 + lane) * 8);
        const bf16x8 a1 = *(const bf16x8*)(ldsW + ((qt * 2 + 1) * 64 + lane) * 8);
        const f4 bov = *(const f4*)(bo + qt * 16 + h * 4);
        f32x4 c = {bov.x, bov.y, bov.z, bov.w};
        c = __builtin_amdgcn_mfma_f32_16x16x32_bf16(a0, blo, c, 0, 0, 0);
        c = __builtin_amdgcn_mfma_f32_16x16x32_bf16(a1, bhi, c, 0, 0, 0);
#pragma unroll
        for (int r = 0; r < 4; ++r) lg[qt * 4 + r] = c[r];
    }

    // LSE across lanes {i, i+16, i+32, i+48}
    float m = lg[0];
#pragma unroll
    for (int j = 1; j < 64; ++j) m = fmaxf(m, lg[j]);
    m = fmaxf(m, __shfl_xor(m, 16, 64));
    m = fmaxf(m, __shfl_xor(m, 32, 64));
    float s = 0.0f;
#pragma unroll
    for (int j = 0; j < 64; ++j) s += __expf(lg[j] - m);
    s += __shfl_xor(s, 16, 64);
    s += __shfl_xor(s, 32, 64);
    const float lse = m + __logf(s);
    const bool valid = n < lengths[b];

    // write: q = qt*16 + h*4 + r at out[b][q][n] (full 64B lines per h-group)
    float* ob = out + (size_t)b * 256 * NN + n;
#pragma unroll
    for (int qt = 0; qt < 16; ++qt)
#pragma unroll
        for (int r = 0; r < 4; ++r)
            ob[(size_t)(qt * 16 + h * 4 + r) * NN] = valid ? (lg[qt * 4 + r] - lse) : 0.0f;
}

extern "C" void kernel_launch(void* const* d_in, const int* in_sizes, int n_in,
                              void* d_out, int out_size, void* d_ws, size_t ws_size,
                              hipStream_t stream)
{
    const float* x       = (const float*)d_in[0];
    const int*   lengths = (const int*)d_in[1];
    const float* W0      = (const float*)d_in[2];
    const float* b0      = (const float*)d_in[3];
    const float* Wf      = (const float*)d_in[4];
    const float* bf      = (const float*)d_in[5];
    const float* Wg      = (const float*)d_in[6];
    const float* bg      = (const float*)d_in[7];
    const float* Wr      = (const float*)d_in[8];
    const float* br      = (const float*)d_in[9];
    const float* Wa      = (const float*)d_in[10];
    const float* ba      = (const float*)d_in[11];
    const float* Wo      = (const float*)d_in[12];
    const float* bo      = (const float*)d_in[13];
    float* out = (float*)d_out;

    short* bufA = (short*)d_ws;                         // (B,N,16) bf16, 4.2 MB
    short* bufB = bufA + (size_t)NPOSTOT * NC;
    short* pk   = bufB + (size_t)NPOSTOT * NC;          // packed weight frags

    prepack_k<<<dim3((PK_TOT + 255) / 256), dim3(256), 0, stream>>>(
        Wf, Wg, Wr, Wa, Wo, pk);

#define FUSED(K, SRC, DST)                                                     \
    fused_t<K><<<dim3(NPOSTOT / CFGS[K].tout),                                 \
                 dim3(CFGS[K].tout + CFGS[K].H), 0, stream>>>(                 \
        SRC, x, W0, b0, DST, pk, bf, bg, br)

    FUSED(0,  bufA, bufA);   // src unused (l0 mode)
    FUSED(1,  bufA, bufB);
    FUSED(2,  bufB, bufA);
    FUSED(3,  bufA, bufB);
    FUSED(4,  bufB, bufA);
    FUSED(5,  bufA, bufB);
    FUSED(6,  bufB, bufA);
    FUSED(7,  bufA, bufB);
    FUSED(8,  bufB, bufA);
    FUSED(9,  bufA, bufB);
    FUSED(10, bufB, bufA);
    FUSED(11, bufA, bufB);
#undef FUSED

    headm_k<<<dim3(NPOSTOT / 128), dim3(512), 0, stream>>>(
        bufB, x, lengths, pk + OFF_WA, ba, pk + OFF_WO, bo, out);
}